// Round 4
// baseline (3373.874 us; speedup 1.0000x reference)
//
#include <hip/hip_runtime.h>

typedef float f4 __attribute__((ext_vector_type(4)));

__device__ __forceinline__ float fsig(float x) {
    float e = __builtin_amdgcn_exp2f(x * -1.4426950408889634f);
    return __builtin_amdgcn_rcpf(1.0f + e);
}
__device__ __forceinline__ float ftanh(float x) {
    float e = __builtin_amdgcn_exp2f(x * -2.8853900817779268f); // e^{-2x}
    return 2.0f * __builtin_amdgcn_rcpf(1.0f + e) - 1.0f;
}

// Barrier for LDS-only exchange: wait own ds ops, s_barrier, but do NOT drain
// vmcnt -- global weight loads stay in flight across layer boundaries.
__device__ __forceinline__ void lds_barrier() {
    asm volatile("s_waitcnt lgkmcnt(0)\n\ts_barrier" ::: "memory");
}

// ws layout (floats):
//   Wmain [l][j][k][g] : 4*32*64*4 = 32768   (l0: k<32 = W_hh[0]; k>=32 zero.
//                                             l>=1: k<32 = W_ih[l-1], k>=32 = W_hh[l])
//   WX0   [j][xk][g]   @ 32768 : 256          (W_ih0 columns)
//   BS    [l][j][g]    @ 33024 : 512          (b_ih + b_hh)
__global__ void pack_weights(const float* __restrict__ Wih0, const float* __restrict__ Wih,
                             const float* __restrict__ Whh,  const float* __restrict__ bih,
                             const float* __restrict__ bhh,  float* __restrict__ ws) {
    int idx = blockIdx.x * 256 + threadIdx.x;
    if (idx < 32768) {
        int g = idx & 3, k = (idx >> 2) & 63, j = (idx >> 8) & 31, l = idx >> 13;
        int row = g * 32 + j;
        float v = 0.0f;
        if (l == 0) {
            if (k < 32) v = Whh[row * 32 + k];
        } else {
            v = (k < 32) ? Wih[(l - 1) * 4096 + row * 32 + k]
                         : Whh[l * 4096 + row * 32 + (k - 32)];
        }
        ws[idx] = v;
    } else if (idx < 33024) {
        int r = idx - 32768;                  // (j*2+xk)*4+g
        int g = r & 3, xk = (r >> 2) & 1, j = r >> 3;
        ws[idx] = Wih0[(g * 32 + j) * 2 + xk];
    } else if (idx < 33536) {
        int r = idx - 33024;                  // (l*32+j)*4+g
        int g = r & 3, j = (r >> 2) & 31, l = r >> 7;
        int row = g * 32 + j;
        ws[idx] = bih[l * 128 + row] + bhh[l * 128 + row];
    }
}

// block = 512 threads = 8 waves. lane = batch row (64 rows/block); wave wv owns
// hidden units wv*4..wv*4+3 across all layers. h exchanged via LDS f4-packed
// [l][parity][kq][lane]; each wave's h-write is exactly one ds_write_b128.
// Weights stream through vmem (per-lane opaque-zero offset defeats scalarization),
// so their waits (vmcnt) are decoupled from LDS waits (lgkmcnt).
__global__ __launch_bounds__(512, 2)
void lstm_fused(const float* __restrict__ xg, const float* __restrict__ ws,
                const float* __restrict__ Wlin, const float* __restrict__ blin,
                float* __restrict__ out) {
    __shared__ f4 H[4 * 2 * 8 * 64];     // [l][p][kq][lane]  64 KB
    const int tid  = threadIdx.x;
    const int lane = tid & 63;
    const int wv   = __builtin_amdgcn_readfirstlane(tid >> 6);   // 0..7 uniform
    const int j0   = wv * 4;
    const int row  = blockIdx.x * 64 + lane;
    const int lz   = __builtin_amdgcn_mbcnt_lo(0u, 0u);          // == 0, opaque

    const f4* W4  = (const f4*)ws;
    const f4* WX0 = (const f4*)(ws + 32768);
    const f4* BS  = (const f4*)(ws + 33024);

    // zero parity-0 h for all layers (t=0 recurrent input)
    {
        f4 z = {0.f, 0.f, 0.f, 0.f};
        for (int i = tid; i < 2048; i += 512) {
            int l = i >> 9, r = i & 511;
            H[l * 1024 + r] = z;
        }
    }

    float c[4][4];
#pragma unroll
    for (int l = 0; l < 4; ++l)
#pragma unroll
        for (int u = 0; u < 4; ++u) c[l][u] = 0.0f;

    const float* xr = xg + (size_t)row * 192;
    float xc0 = xr[0], xc1 = xr[64];

    __syncthreads();

    for (int t = 0; t < 64; ++t) {
        const int prevp = t & 1;
        const int curp  = prevp ^ 1;
        const int tn = (t < 63) ? (t + 1) : 63;
        float xn0 = xr[tn], xn1 = xr[64 + tn];

        // ---------------- layer 0 ----------------
        {
            f4 acc[4];
#pragma unroll
            for (int u = 0; u < 4; ++u) {
                f4 b   = BS[j0 + u];
                f4 wa  = WX0[(j0 + u) * 2 + 0];
                f4 wb2 = WX0[(j0 + u) * 2 + 1];
                acc[u] = b + wa * xc0 + wb2 * xc1;
            }
            const f4* wb = W4 + j0 * 64 + lz;           // layer-0 slice, vmem
            const f4* hr = H + prevp * 512;             // [0][prevp]
#pragma unroll 4
            for (int kq = 0; kq < 8; ++kq) {
                f4 hv = hr[kq * 64 + lane];
#pragma unroll
                for (int u = 0; u < 4; ++u) {
                    acc[u] += wb[u * 64 + kq * 4 + 0] * hv.x;
                    acc[u] += wb[u * 64 + kq * 4 + 1] * hv.y;
                    acc[u] += wb[u * 64 + kq * 4 + 2] * hv.z;
                    acc[u] += wb[u * 64 + kq * 4 + 3] * hv.w;
                }
            }
            float hn[4];
#pragma unroll
            for (int u = 0; u < 4; ++u) {
                float ig = fsig(acc[u].x), fg = fsig(acc[u].y);
                float gg = ftanh(acc[u].z), og = fsig(acc[u].w);
                float cn = fg * c[0][u] + ig * gg;
                c[0][u] = cn;
                hn[u] = og * ftanh(cn);
            }
            f4 hv = {hn[0], hn[1], hn[2], hn[3]};
            H[(curp * 8 + wv) * 64 + lane] = hv;
        }
        lds_barrier();

        // ---------------- layers 1..3 ----------------
#pragma unroll
        for (int l = 1; l < 4; ++l) {
            f4 acc[4];
#pragma unroll
            for (int u = 0; u < 4; ++u) acc[u] = BS[l * 32 + j0 + u];
            const f4* wb = W4 + (l * 32 + j0) * 64 + lz;
            const f4* hi = H + ((l - 1) * 2 + curp) * 512;   // input: h[l-1] this t
            const f4* hr = H + (l * 2 + prevp) * 512;        // recurrent: h[l] prev t
#pragma unroll 4
            for (int kq = 0; kq < 8; ++kq) {
                f4 hv = hi[kq * 64 + lane];
#pragma unroll
                for (int u = 0; u < 4; ++u) {
                    acc[u] += wb[u * 64 + kq * 4 + 0] * hv.x;
                    acc[u] += wb[u * 64 + kq * 4 + 1] * hv.y;
                    acc[u] += wb[u * 64 + kq * 4 + 2] * hv.z;
                    acc[u] += wb[u * 64 + kq * 4 + 3] * hv.w;
                }
            }
#pragma unroll 4
            for (int kq = 0; kq < 8; ++kq) {
                f4 hv = hr[kq * 64 + lane];
#pragma unroll
                for (int u = 0; u < 4; ++u) {
                    acc[u] += wb[u * 64 + 32 + kq * 4 + 0] * hv.x;
                    acc[u] += wb[u * 64 + 32 + kq * 4 + 1] * hv.y;
                    acc[u] += wb[u * 64 + 32 + kq * 4 + 2] * hv.z;
                    acc[u] += wb[u * 64 + 32 + kq * 4 + 3] * hv.w;
                }
            }
            float hn[4];
#pragma unroll
            for (int u = 0; u < 4; ++u) {
                float ig = fsig(acc[u].x), fg = fsig(acc[u].y);
                float gg = ftanh(acc[u].z), og = fsig(acc[u].w);
                float cn = fg * c[l][u] + ig * gg;
                c[l][u] = cn;
                hn[u] = og * ftanh(cn);
            }
            f4 hv = {hn[0], hn[1], hn[2], hn[3]};
            H[((l * 2 + curp) * 8 + wv) * 64 + lane] = hv;
            lds_barrier();
        }

        xc0 = xn0; xc1 = xn1;
    }

    // ---------------- output head: t=63 -> curp==0, h3 at [3][0] ----------------
    if (tid < 64) {
        const f4* h3 = H + 3 * 1024;         // [3][0][kq][lane]
        const f4* WL = (const f4*)Wlin;
        float s = blin[0];
#pragma unroll
        for (int kq = 0; kq < 8; ++kq) {
            f4 w = WL[kq];
            f4 h = h3[kq * 64 + lane];
            s += w.x * h.x + w.y * h.y + w.z * h.z + w.w * h.w;
        }
        out[row] = fsig(s);
    }
}

extern "C" void kernel_launch(void* const* d_in, const int* in_sizes, int n_in,
                              void* d_out, int out_size, void* d_ws, size_t ws_size,
                              hipStream_t stream) {
    const float* x    = (const float*)d_in[0];
    const float* Wih0 = (const float*)d_in[1];
    const float* Wih  = (const float*)d_in[2];
    const float* Whh  = (const float*)d_in[3];
    const float* bih  = (const float*)d_in[4];
    const float* bhh  = (const float*)d_in[5];
    const float* Wlin = (const float*)d_in[6];
    const float* blin = (const float*)d_in[7];
    float* ws  = (float*)d_ws;
    float* out = (float*)d_out;

    pack_weights<<<132, 256, 0, stream>>>(Wih0, Wih, Whh, bih, bhh, ws);
    lstm_fused<<<256, 512, 0, stream>>>(x, ws, Wlin, blin, out);
}

// Round 5
// 244.081 us; speedup vs baseline: 13.8228x; 13.8228x over previous
//
#include <hip/hip_runtime.h>

typedef float  f32x4  __attribute__((ext_vector_type(4)));
typedef short  bf16x8 __attribute__((ext_vector_type(8)));

#define LOG2E    1.4426950408889634f
#define TWOLOG2E 2.8853900817779268f

__device__ __forceinline__ unsigned short f2b(float f) {      // fp32 -> bf16 RNE
    unsigned int u = __builtin_bit_cast(unsigned int, f);
    u += 0x7fffu + ((u >> 16) & 1u);
    return (unsigned short)(u >> 16);
}
__device__ __forceinline__ float b2f(unsigned short s) {
    unsigned int u = ((unsigned int)s) << 16;
    return __builtin_bit_cast(float, u);
}
// sigmoid with input pre-scaled by log2e (folded into weights/bias)
__device__ __forceinline__ float sig2(float xh) {
    return __builtin_amdgcn_rcpf(1.0f + __builtin_amdgcn_exp2f(-xh));
}
// tanh with input pre-scaled by 2*log2e
__device__ __forceinline__ float th2(float xh) {
    return 2.0f * __builtin_amdgcn_rcpf(1.0f + __builtin_amdgcn_exp2f(-xh)) - 1.0f;
}
// tanh of unscaled value (cell state)
__device__ __forceinline__ float thc(float c) {
    return 2.0f * __builtin_amdgcn_rcpf(1.0f + __builtin_amdgcn_exp2f(c * -TWOLOG2E)) - 1.0f;
}

// ws layout: bf16 W[l][G(128)][k(64)] (64 KB), then f32 bias[l][G] at +65536 B (2 KB).
//   l==0: k<2 = W_ih0 cols, 2..31 = 0, k>=32 = W_hh[0] (recurrent)
//   l>=1: k<32 = W_ih[l-1],            k>=32 = W_hh[l]
// Gate rows G = T*32 + j, T in {i,f,g,o}; rows pre-scaled by log2e (2*log2e for T==2).
__global__ void pack_weights(const float* __restrict__ Wih0, const float* __restrict__ Wih,
                             const float* __restrict__ Whh,  const float* __restrict__ bih,
                             const float* __restrict__ bhh,  void* __restrict__ wsv) {
    short* wsb = (short*)wsv;
    float* bsf = (float*)((char*)wsv + 65536);
    int idx = blockIdx.x * 256 + threadIdx.x;
    if (idx < 32768) {
        int k = idx & 63, G = (idx >> 6) & 127, l = idx >> 13;
        float scale = ((G >> 5) == 2) ? TWOLOG2E : LOG2E;
        float v = 0.0f;
        if (l == 0) {
            if (k < 2)        v = Wih0[G * 2 + k];
            else if (k >= 32) v = Whh[G * 32 + (k - 32)];
        } else {
            v = (k < 32) ? Wih[(l - 1) * 4096 + G * 32 + k]
                         : Whh[l * 4096 + G * 32 + (k - 32)];
        }
        wsb[idx] = (short)f2b(v * scale);
    } else if (idx < 33280) {
        int r = idx - 32768;
        int G = r & 127, l = r >> 7;
        float scale = ((G >> 5) == 2) ? TWOLOG2E : LOG2E;
        bsf[r] = (bih[l * 128 + G] + bhh[l * 128 + G]) * scale;
    }
}

// block = 256 thr = 4 waves; 32 batch rows/block (2 M-tiles of 16). Wave l owns
// layer l: its 16 B-frags (128 gates x K=64) live in VGPRs for the whole kernel.
// Software pipeline: at step s, wave l computes t = s-l. h crosses layers through
// LDS in A-frag layout [row][unit] bf16 (stride 40 shorts), parity-double-buffered
// by step. c-state in registers (D-layout gives each lane i,f,g,o of 2 units).
__global__ __launch_bounds__(256, 2)
void lstm_mfma(const float* __restrict__ xg, const void* __restrict__ wsv,
               const float* __restrict__ Wlin, const float* __restrict__ blin,
               float* __restrict__ out) {
    __shared__ short        hb[4 * 2 * 1280] __attribute__((aligned(16))); // [l][p][row32*40]
    __shared__ unsigned int xb[64 * 32];                                   // [t][row] 2xbf16

    const short* wsb = (const short*)wsv;
    const float* bsf = (const float*)((const char*)wsv + 65536);

    const int tid  = threadIdx.x;
    const int wv   = __builtin_amdgcn_readfirstlane(tid >> 6);  // layer id, uniform
    const int lane = tid & 63;
    const int m    = lane & 15;    // A-row / D-col index
    const int q    = lane >> 4;    // quad
    const int row0 = blockIdx.x * 32;

    // zero h buffers (first reads of each parity must see 0)
    for (int i = tid; i < 5120; i += 256) ((unsigned int*)hb)[i] = 0u;

    // stage x -> LDS bf16 [t][row] (coalesced global reads)
    for (int i = tid; i < 2048; i += 256) {
        int r = i >> 6, t = i & 63;
        float x0 = xg[(size_t)(row0 + r) * 192 + t];
        float x1 = xg[(size_t)(row0 + r) * 192 + 64 + t];
        xb[t * 32 + r] = (unsigned int)f2b(x0) | ((unsigned int)f2b(x1) << 16);
    }

    // persistent B-frags: lane holds W[G = g*16+m][k = c*32 + q*8 .. +7]
    bf16x8 bfr[8][2];
#pragma unroll
    for (int g = 0; g < 8; ++g)
#pragma unroll
        for (int c = 0; c < 2; ++c)
            bfr[g][c] = *(const bf16x8*)(wsb + ((wv * 128 + g * 16 + m) * 64 + c * 32 + q * 8));

    float bias_v[8];
#pragma unroll
    for (int g = 0; g < 8; ++g) bias_v[g] = bsf[wv * 128 + g * 16 + m];

    float cst[2][2][4];
#pragma unroll
    for (int tt = 0; tt < 2; ++tt)
#pragma unroll
        for (int u = 0; u < 2; ++u)
#pragma unroll
            for (int r = 0; r < 4; ++r) cst[tt][u][r] = 0.0f;

    __syncthreads();

    for (int s = 0; s < 67; ++s) {
        const int t = s - wv;                 // wave-uniform
        if (t >= 0 && t < 64) {
            const int rp = (s - 1) & 1;       // read parity (s=0 -> 1, zero-init)
            const int wp = s & 1;             // write parity
            short*       hw    = hb + (wv * 2 + wp) * 1280;
            const short* hrin  = hb + (((wv > 0 ? wv - 1 : 0) * 2) + rp) * 1280;
            const short* hrrec = hb + (wv * 2 + rp) * 1280;
#pragma unroll
            for (int tt = 0; tt < 2; ++tt) {
                bf16x8 a0;
                if (wv == 0) {
                    unsigned int xd = xb[t * 32 + tt * 16 + m];
                    bf16x8 z = (bf16x8)0;
                    a0 = z;
                    if (q == 0) { a0[0] = (short)(xd & 0xffffu); a0[1] = (short)(xd >> 16); }
                } else {
                    a0 = *(const bf16x8*)(hrin + (tt * 16 + m) * 40 + q * 8);
                }
                bf16x8 a1 = *(const bf16x8*)(hrrec + (tt * 16 + m) * 40 + q * 8);

                f32x4 acc[8];
#pragma unroll
                for (int g = 0; g < 8; ++g) {
                    f32x4 zz = {0.f, 0.f, 0.f, 0.f};
                    acc[g] = __builtin_amdgcn_mfma_f32_16x16x32_bf16(a0, bfr[g][0], zz, 0, 0, 0);
                    acc[g] = __builtin_amdgcn_mfma_f32_16x16x32_bf16(a1, bfr[g][1], acc[g], 0, 0, 0);
                }
                // lane holds rows q*4+r of: unit m (g even) and unit m+16 (g odd)
#pragma unroll
                for (int r = 0; r < 4; ++r) {
                    float iA = sig2(acc[0][r] + bias_v[0]);
                    float fA = sig2(acc[2][r] + bias_v[2]);
                    float gA = th2 (acc[4][r] + bias_v[4]);
                    float oA = sig2(acc[6][r] + bias_v[6]);
                    float cA = fA * cst[tt][0][r] + iA * gA;
                    cst[tt][0][r] = cA;
                    float hA = oA * thc(cA);

                    float iB = sig2(acc[1][r] + bias_v[1]);
                    float fB = sig2(acc[3][r] + bias_v[3]);
                    float gB = th2 (acc[5][r] + bias_v[5]);
                    float oB = sig2(acc[7][r] + bias_v[7]);
                    float cB = fB * cst[tt][1][r] + iB * gB;
                    cst[tt][1][r] = cB;
                    float hB = oB * thc(cB);

                    int rowi = tt * 16 + q * 4 + r;
                    hw[rowi * 40 + m]      = (short)f2b(hA);
                    hw[rowi * 40 + m + 16] = (short)f2b(hB);
                }
            }
        }
        __syncthreads();
    }

    // output head: h[3][t=63] written at s=66 -> parity 0
    if (tid < 32) {
        const short* h3 = hb + (3 * 2 + 0) * 1280;
        float s = blin[0];
#pragma unroll
        for (int k = 0; k < 32; ++k)
            s += Wlin[k] * b2f((unsigned short)h3[tid * 40 + k]);
        out[row0 + tid] = sig2(s * LOG2E);
    }
}

extern "C" void kernel_launch(void* const* d_in, const int* in_sizes, int n_in,
                              void* d_out, int out_size, void* d_ws, size_t ws_size,
                              hipStream_t stream) {
    const float* x    = (const float*)d_in[0];
    const float* Wih0 = (const float*)d_in[1];
    const float* Wih  = (const float*)d_in[2];
    const float* Whh  = (const float*)d_in[3];
    const float* bih  = (const float*)d_in[4];
    const float* bhh  = (const float*)d_in[5];
    const float* Wlin = (const float*)d_in[6];
    const float* blin = (const float*)d_in[7];
    float* out = (float*)d_out;

    pack_weights<<<130, 256, 0, stream>>>(Wih0, Wih, Whh, bih, bhh, d_ws);
    lstm_mfma<<<512, 256, 0, stream>>>(x, d_ws, Wlin, blin, out);
}